// Round 4
// baseline (6664.034 us; speedup 1.0000x reference)
//
#include <hip/hip_runtime.h>
#include <math.h>

// ---------------- constants ----------------
// E=1024, T=12, CPT=4, D=64, NH=4, HD=16, FF=256, L=2
// 256 spatial cells (blocks); per cell 256 sequences of (T=12, D=64).
// Phase 3: lane = (sl, t): sl = sub-sequence slot 0..4 (5 seqs/wave), t = 0..11.
// 8 waves x 5 seqs = 40 seqs per pass, 7 passes cover 256.
//
// R2 change (resubmitted in R3 after container failure): pin
// amdgpu_waves_per_eu(2,2). LDS (120KB) already caps us at 1 block/CU =
// 2 waves/EU, so this is free occupancy-wise but raises the VGPR budget
// 128->256, eliminating the 7 GB/dispatch scratch spill traffic observed
// in R1 (WRITE_SIZE 4.2GB, VGPR_Count 128 vs ~160 live).

#define LGKM0 asm volatile("s_waitcnt lgkmcnt(0)" ::: "memory")

// 4-output-row matmul quad: A0..A3 = bias[R..R+3] + W[R..R+3][:] . SRC[0:64]
#define QUAD_MM(WROW, BPTR, R, A0, A1, A2, A3, SRC)                         \
  {                                                                         \
    const float* _w = (WROW);                                               \
    A0 = (BPTR)[(R)];                                                       \
    A1 = (BPTR)[(R) + 1];                                                   \
    A2 = (BPTR)[(R) + 2];                                                   \
    A3 = (BPTR)[(R) + 3];                                                   \
    _Pragma("unroll") for (int _d = 0; _d < 64; ++_d) {                     \
      float _hv = SRC[_d];                                                  \
      A0 = fmaf(_w[_d], _hv, A0);                                           \
      A1 = fmaf(_w[64 + _d], _hv, A1);                                      \
      A2 = fmaf(_w[128 + _d], _hv, A2);                                     \
      A3 = fmaf(_w[192 + _d], _hv, A3);                                     \
    }                                                                       \
  }

#define LAYERNORM(GP, BP)                                                   \
  {                                                                         \
    float s1[32];                                                           \
    _Pragma("unroll") for (int i = 0; i < 32; ++i)                          \
        s1[i] = h[2 * i] + h[2 * i + 1];                                    \
    _Pragma("unroll") for (int i = 0; i < 16; ++i) s1[i] += s1[i + 16];     \
    _Pragma("unroll") for (int i = 0; i < 8; ++i) s1[i] += s1[i + 8];       \
    _Pragma("unroll") for (int i = 0; i < 4; ++i) s1[i] += s1[i + 4];       \
    float m_ = (s1[0] + s1[1] + s1[2] + s1[3]) * (1.f / 64.f);              \
    float q1[32];                                                           \
    _Pragma("unroll") for (int i = 0; i < 32; ++i) {                        \
      float d0_ = h[2 * i] - m_, d1_ = h[2 * i + 1] - m_;                   \
      q1[i] = fmaf(d0_, d0_, d1_ * d1_);                                    \
    }                                                                       \
    _Pragma("unroll") for (int i = 0; i < 16; ++i) q1[i] += q1[i + 16];     \
    _Pragma("unroll") for (int i = 0; i < 8; ++i) q1[i] += q1[i + 8];       \
    _Pragma("unroll") for (int i = 0; i < 4; ++i) q1[i] += q1[i + 4];       \
    float v_ = (q1[0] + q1[1] + q1[2] + q1[3]) * (1.f / 64.f);              \
    float rs_ = rsqrtf(v_ + 1e-5f);                                         \
    _Pragma("unroll") for (int d = 0; d < 64; ++d)                          \
        h[d] = fmaf((h[d] - m_) * rs_, (GP)[d], (BP)[d]);                   \
  }

__global__ __launch_bounds__(512)
__attribute__((amdgpu_waves_per_eu(2, 2)))
void prithvi_fused(
    const float* __restrict__ x,     const float* __restrict__ conv_w,
    const float* __restrict__ bn_g,  const float* __restrict__ bn_b,
    const float* __restrict__ bn_m,  const float* __restrict__ bn_v,
    const float* __restrict__ w_in,  const float* __restrict__ qkv_w,
    const float* __restrict__ qkv_b, const float* __restrict__ ow,
    const float* __restrict__ ob,    const float* __restrict__ ln1_g,
    const float* __restrict__ ln1_b, const float* __restrict__ ff1_w,
    const float* __restrict__ ff1_b, const float* __restrict__ ff2_w,
    const float* __restrict__ ff2_b, const float* __restrict__ ln2_g,
    const float* __restrict__ ln2_b, const float* __restrict__ w_out,
    const float* __restrict__ b_out, float* __restrict__ out)
{
  // sbuf: phase1 = x-slice transposed [t][e] (12x1024); phase2 output g [o][t] (1024x12)
  __shared__ __align__(16) float sbuf[12288];              // 48 KB
  // per-wave row buffer: 64 rows x 36 words (rows: row = t*5+sl)
  __shared__ __align__(16) float Tbuf[8 * 64 * 36];        // 72 KB

  const int sp   = blockIdx.x;    // hp*16 + wp
  const int tid  = threadIdx.x;
  const int lane = tid & 63;
  const int wave = tid >> 6;

  // ---------------- phase 1: stage x slice transposed: sbuf[t*1024+e] ----------------
  for (int ch = tid; ch < 12288; ch += 512) {
    int e = ch / 12;
    int t = ch - e * 12;
    sbuf[t * 1024 + e] = x[(size_t)ch * 256 + sp];
  }
  __syncthreads();

  // ---------------- phase 2: 1x1 conv (acc in regs) ----------------
  float acc0[12], acc1[12];
#pragma unroll
  for (int t = 0; t < 12; ++t) { acc0[t] = 0.f; acc1[t] = 0.f; }
  {
    const float* w0p = conv_w + tid * 1024;
    const float* w1p = conv_w + (tid + 512) * 1024;
    for (int eb = 0; eb < 1024; eb += 4) {
      float4 wa = *(const float4*)(w0p + eb);
      float4 wb = *(const float4*)(w1p + eb);
#pragma unroll
      for (int t = 0; t < 12; ++t) {
        float4 xv = *(const float4*)&sbuf[t * 1024 + eb];
        acc0[t] = fmaf(xv.x, wa.x, acc0[t]);
        acc0[t] = fmaf(xv.y, wa.y, acc0[t]);
        acc0[t] = fmaf(xv.z, wa.z, acc0[t]);
        acc0[t] = fmaf(xv.w, wa.w, acc0[t]);
        acc1[t] = fmaf(xv.x, wb.x, acc1[t]);
        acc1[t] = fmaf(xv.y, wb.y, acc1[t]);
        acc1[t] = fmaf(xv.z, wb.z, acc1[t]);
        acc1[t] = fmaf(xv.w, wb.w, acc1[t]);
      }
    }
  }
  __syncthreads();   // all xs reads done; sbuf now becomes g
  {
    int o0 = tid;
    float sc0 = bn_g[o0] * rsqrtf(bn_v[o0] + 1e-5f);
    float sh0 = fmaf(-bn_m[o0], sc0, bn_b[o0]);
#pragma unroll
    for (int t = 0; t < 12; ++t) {
      float z = fmaf(acc0[t], sc0, sh0);
      sbuf[o0 * 12 + t] = 0.5f * z * (1.f + erff(z * 0.70710678118654752f));
    }
    int o1 = tid + 512;
    float sc1 = bn_g[o1] * rsqrtf(bn_v[o1] + 1e-5f);
    float sh1 = fmaf(-bn_m[o1], sc1, bn_b[o1]);
#pragma unroll
    for (int t = 0; t < 12; ++t) {
      float z = fmaf(acc1[t], sc1, sh1);
      sbuf[o1 * 12 + t] = 0.5f * z * (1.f + erff(z * 0.70710678118654752f));
    }
  }
  __syncthreads();
  // sbuf (= g[o*12+t]) read-only from here.

  // ---------------- phase 3: lane = (sl, t) ----------------
  const int sl  = lane / 12;                 // 0..5 (5 = idle slot)
  const int t   = lane - sl * 12;            // 0..11 (0..3 for sl==5)
  const int slc = (sl < 5) ? sl : 4;         // clamped for reads
  const int rowi = (sl < 5) ? (t * 5 + sl) : (60 + t);
  float* Tw   = Tbuf + wave * (64 * 36);
  float* rowW = Tw + rowi * 36;
  const float tf = (float)t;

#pragma unroll 1
  for (int it = 0; it < 7; ++it) {
    const int s_raw = it * 40 + wave * 5 + sl;
    const bool valid = (sl < 5) && (s_raw < 256);
    const int s = valid ? s_raw : 0;

    // ---- h0 = g4 @ w_in.T + pos_encoding ----
    float h[64];
    {
      const int gb = s * 12 + t;
      const float g0 = sbuf[gb];
      const float g1 = sbuf[3072 + gb];
      const float g2 = sbuf[6144 + gb];
      const float g3 = sbuf[9216 + gb];
      float freq = 1.f;                       // exp(-2i*ln(1e4)/64)^i, i=0..31
#pragma unroll
      for (int i = 0; i < 32; ++i) {
        float ang = tf * freq;
        float sv = sinf(ang), cv = cosf(ang);
        const float* wi = w_in + 8 * i;
        h[2 * i]     = fmaf(g0, wi[0], fmaf(g1, wi[1], fmaf(g2, wi[2], fmaf(g3, wi[3], sv))));
        h[2 * i + 1] = fmaf(g0, wi[4], fmaf(g1, wi[5], fmaf(g2, wi[6], fmaf(g3, wi[7], cv))));
        freq *= 0.74989420933245580f;         // exp(-2*ln(1e4)/64)
      }
    }

#pragma unroll 1
    for (int l = 0; l < 2; ++l) {
      const float* Wb = qkv_w + l * 192 * 64;
      const float* Bb = qkv_b + l * 192;
      float att[2][12];
      float o[64];
#pragma unroll
      for (int d = 0; d < 64; ++d) o[d] = 0.f;

#pragma unroll
      for (int half = 0; half < 2; ++half) {
        // ---- K chunk (k dims half*32 .. +31) -> LDS words 0..31 ----
        LGKM0;
#pragma unroll 1
        for (int dp = 0; dp < 32; dp += 4) {
          int r = 64 + half * 32 + dp;
          float a0, a1, a2, a3;
          QUAD_MM(Wb + r * 64, Bb, r, a0, a1, a2, a3, h);
          *(float4*)(rowW + dp) = make_float4(a0, a1, a2, a3);
        }
        LGKM0;
        // ---- Q (heads 2*half, 2*half+1) fused with scores ----
#pragma unroll
        for (int hp = 0; hp < 2; ++hp) {
#pragma unroll
          for (int tk = 0; tk < 12; ++tk) att[hp][tk] = 0.f;
#pragma unroll 1
          for (int qq = 0; qq < 4; ++qq) {
            int r = half * 32 + hp * 16 + qq * 4;   // q row
            float a0, a1, a2, a3;
            QUAD_MM(Wb + r * 64, Bb, r, a0, a1, a2, a3, h);
            int w = hp * 16 + qq * 4;               // k word in row
#pragma unroll
            for (int tk = 0; tk < 12; ++tk) {
              const float4 kv = *(const float4*)(Tw + (tk * 5 + slc) * 36 + w);
              att[hp][tk] = fmaf(a0, kv.x, fmaf(a1, kv.y, fmaf(a2, kv.z, fmaf(a3, kv.w, att[hp][tk]))));
            }
          }
          // softmax (lane-local), scale 1/sqrt(16)=0.25 folded in
          float mx = att[hp][0];
#pragma unroll
          for (int tk = 1; tk < 12; ++tk) mx = fmaxf(mx, att[hp][tk]);
          float sum = 0.f;
#pragma unroll
          for (int tk = 0; tk < 12; ++tk) {
            float e = expf((att[hp][tk] - mx) * 0.25f);
            att[hp][tk] = e;
            sum += e;
          }
          float inv = 1.f / sum;
#pragma unroll
          for (int tk = 0; tk < 12; ++tk) att[hp][tk] *= inv;
        }
        // ---- V chunk (v dims half*32 .. +31) ----
        LGKM0;
#pragma unroll 1
        for (int dp = 0; dp < 32; dp += 4) {
          int r = 128 + half * 32 + dp;
          float a0, a1, a2, a3;
          QUAD_MM(Wb + r * 64, Bb, r, a0, a1, a2, a3, h);
          *(float4*)(rowW + dp) = make_float4(a0, a1, a2, a3);
        }
        LGKM0;
        // ---- PV: o[half*32 .. +31] ----
#pragma unroll
        for (int tk = 0; tk < 12; ++tk) {
          const float* vr = Tw + (tk * 5 + slc) * 36;
          float a0 = att[0][tk], a1 = att[1][tk];
#pragma unroll
          for (int dq = 0; dq < 8; ++dq) {
            float4 vv = *(const float4*)(vr + dq * 4);
            float aa = (dq < 4) ? a0 : a1;
            int ob_ = half * 32 + dq * 4;
            o[ob_ + 0] = fmaf(aa, vv.x, o[ob_ + 0]);
            o[ob_ + 1] = fmaf(aa, vv.y, o[ob_ + 1]);
            o[ob_ + 2] = fmaf(aa, vv.z, o[ob_ + 2]);
            o[ob_ + 3] = fmaf(aa, vv.w, o[ob_ + 3]);
          }
        }
      } // half

      // ---- o-proj + residual (two halves through LDS row) ----
      {
        const float* WO  = ow + l * 64 * 64;
        const float* BOp = ob + l * 64;
#pragma unroll
        for (int half = 0; half < 2; ++half) {
          LGKM0;
#pragma unroll 1
          for (int dp = 0; dp < 32; dp += 4) {
            int r = half * 32 + dp;
            float a0, a1, a2, a3;
            QUAD_MM(WO + r * 64, BOp, r, a0, a1, a2, a3, o);
            *(float4*)(rowW + dp) = make_float4(a0, a1, a2, a3);
          }
          LGKM0;
#pragma unroll
          for (int dq = 0; dq < 8; ++dq) {
            float4 r4 = *(const float4*)(rowW + dq * 4);
            int hb = half * 32 + dq * 4;
            h[hb + 0] += r4.x;
            h[hb + 1] += r4.y;
            h[hb + 2] += r4.z;
            h[hb + 3] += r4.w;
          }
        }
      }
      // ---- LN1 ----
      LAYERNORM(ln1_g + l * 64, ln1_b + l * 64);

      // ---- FF: chunks of 32 ff-dims through LDS row ----
      {
        float facc[64];
#pragma unroll
        for (int d = 0; d < 64; ++d) facc[d] = ff2_b[l * 64 + d];
        const float* W1 = ff1_w + l * 256 * 64;
        const float* B1 = ff1_b + l * 256;
        const float* W2 = ff2_w + l * 64 * 256;
#pragma unroll 1
        for (int chk = 0; chk < 8; ++chk) {
          LGKM0;
#pragma unroll 1
          for (int fp = 0; fp < 32; fp += 4) {
            int r = chk * 32 + fp;
            float a0, a1, a2, a3;
            QUAD_MM(W1 + r * 64, B1, r, a0, a1, a2, a3, h);
            a0 = fmaxf(a0, 0.f);
            a1 = fmaxf(a1, 0.f);
            a2 = fmaxf(a2, 0.f);
            a3 = fmaxf(a3, 0.f);
            *(float4*)(rowW + fp) = make_float4(a0, a1, a2, a3);
          }
          LGKM0;
#pragma unroll 1
          for (int sub = 0; sub < 4; ++sub) {
            float4 xa = *(const float4*)(rowW + sub * 8);
            float4 xb = *(const float4*)(rowW + sub * 8 + 4);
            int cb = chk * 32 + sub * 8;
#pragma unroll
            for (int d2 = 0; d2 < 64; ++d2) {
              const float* w2r = W2 + d2 * 256 + cb;
              float t0 = fmaf(w2r[0], xa.x, facc[d2]);
              t0 = fmaf(w2r[1], xa.y, t0);
              t0 = fmaf(w2r[2], xa.z, t0);
              t0 = fmaf(w2r[3], xa.w, t0);
              t0 = fmaf(w2r[4], xb.x, t0);
              t0 = fmaf(w2r[5], xb.y, t0);
              t0 = fmaf(w2r[6], xb.z, t0);
              facc[d2] = fmaf(w2r[7], xb.w, t0);
            }
          }
        }
#pragma unroll
        for (int d = 0; d < 64; ++d) h[d] += facc[d];
      }
      // ---- LN2 ----
      LAYERNORM(ln2_g + l * 64, ln2_b + l * 64);
    } // layer

    // ---- head: mean over t, dot w_out, sigmoid ----
    {
      float p = 0.f;
#pragma unroll
      for (int d = 0; d < 64; ++d) p = fmaf(h[d], w_out[d], p);
      LGKM0;
      rowW[0] = p;
      LGKM0;
      float ps = 0.f;
#pragma unroll
      for (int tk = 0; tk < 12; ++tk) ps += Tw[(tk * 5 + slc) * 36];
      if (valid && t == 0) {
        float logit = ps * (1.f / 12.f) + b_out[0];
        int hf = ((sp >> 4) << 4) | (s_raw >> 4);
        int wf = ((sp & 15) << 4) | (s_raw & 15);
        out[hf * 256 + wf] = 1.f / (1.f + expf(-logit));
      }
    }
  } // pass loop
}

extern "C" void kernel_launch(void* const* d_in, const int* in_sizes, int n_in,
                              void* d_out, int out_size, void* d_ws, size_t ws_size,
                              hipStream_t stream) {
  (void)in_sizes; (void)n_in; (void)d_ws; (void)ws_size; (void)out_size;
  prithvi_fused<<<256, 512, 0, stream>>>(
    (const float*)d_in[0],  (const float*)d_in[1],  (const float*)d_in[2],
    (const float*)d_in[3],  (const float*)d_in[4],  (const float*)d_in[5],
    (const float*)d_in[6],  (const float*)d_in[7],  (const float*)d_in[8],
    (const float*)d_in[9],  (const float*)d_in[10], (const float*)d_in[11],
    (const float*)d_in[12], (const float*)d_in[13], (const float*)d_in[14],
    (const float*)d_in[15], (const float*)d_in[16], (const float*)d_in[17],
    (const float*)d_in[18], (const float*)d_in[19], (const float*)d_in[20],
    (float*)d_out);
}